// Round 15
// baseline (269.493 us; speedup 1.0000x reference)
//
#include <hip/hip_runtime.h>

typedef unsigned short ushort_t;
typedef __bf16 bf16x8 __attribute__((ext_vector_type(8)));
typedef float f32x4 __attribute__((ext_vector_type(4)));

#define S_LEN 2048
#define DMODEL 2048
#define NH 16
#define HDIM 128
#define BATCH 2
#define M_ROWS (BATCH * S_LEN) // 4096

__device__ __forceinline__ ushort_t f2bf(float f) {
    union { float f; unsigned u; } v; v.f = f;
    unsigned r = (v.u + 0x7fffu + ((v.u >> 16) & 1u)) >> 16;
    return (ushort_t)r;
}
__device__ __forceinline__ float bf2f(ushort_t u) {
    union { unsigned u; float f; } v; v.u = ((unsigned)u) << 16;
    return v.f;
}

__device__ __forceinline__ void async16(const void* g, void* l) {
    __builtin_amdgcn_global_load_lds(
        (const __attribute__((address_space(1))) void*)g,
        (__attribute__((address_space(3))) void*)l, 16, 0, 0);
}

// ---------------- fp32 -> bf16 (4 elems/thread) ----------------
__global__ void cvt_bf16(const float* __restrict__ in, ushort_t* __restrict__ out, int n4) {
    int i = blockIdx.x * blockDim.x + threadIdx.x;
    if (i >= n4) return;
    float4 f = ((const float4*)in)[i];
    ushort4 u;
    u.x = f2bf(f.x); u.y = f2bf(f.y); u.z = f2bf(f.z); u.w = f2bf(f.w);
    ((ushort4*)out)[i] = u;
}

// ---------------- fp32 -> bf16 for the 4 weight matrices in one launch ----------
__global__ void cvt4_bf16(const float* __restrict__ w0, const float* __restrict__ w1,
                          const float* __restrict__ w2, const float* __restrict__ w3,
                          ushort_t* __restrict__ out, int n4) {
    int i = blockIdx.x * blockDim.x + threadIdx.x;
    if (i >= n4) return;
    int which = blockIdx.y;
    const float* src = which == 0 ? w0 : which == 1 ? w1 : which == 2 ? w2 : w3;
    float4 f = ((const float4*)src)[i];
    ushort4 u;
    u.x = f2bf(f.x); u.y = f2bf(f.y); u.z = f2bf(f.z); u.w = f2bf(f.w);
    ((ushort4*)(out + (size_t)which * DMODEL * DMODEL))[i] = u;
}

// ---------------- RoPE tables [S][64] ----------------
__global__ void rope_tables(float* __restrict__ cosT, float* __restrict__ sinT) {
    int i = blockIdx.x * blockDim.x + threadIdx.x; // 2048*64
    int s = i >> 6, f = i & 63;
    float inv = powf(10000.0f, -(float)(2 * f) / 128.0f);
    float ang = (float)s * inv;
    cosT[i] = cosf(ang);
    sinT[i] = sinf(ang);
}

// ---------------- RoPE in-place on Q and K ([BH][S][HD] bf16) ----------------
__global__ void rope_inplace(ushort_t* __restrict__ Q, ushort_t* __restrict__ K,
                             const float* __restrict__ cosT, const float* __restrict__ sinT) {
    long i = (long)blockIdx.x * blockDim.x + threadIdx.x; // 32*2048*64
    int f = (int)(i & 63);
    long t = i >> 6;
    int s = (int)(t & (S_LEN - 1));
    int bh = (int)(t >> 11);
    long base = ((long)bh * S_LEN + s) * HDIM;
    float c = cosT[s * 64 + f], sn = sinT[s * 64 + f];
    float a0 = bf2f(Q[base + f]), a1 = bf2f(Q[base + 64 + f]);
    Q[base + f]      = f2bf(a0 * c - a1 * sn);
    Q[base + 64 + f] = f2bf(a1 * c + a0 * sn);
    float b0 = bf2f(K[base + f]), b1 = bf2f(K[base + 64 + f]);
    K[base + f]      = f2bf(b0 * c - b1 * sn);
    K[base + 64 + f] = f2bf(b1 * c + b0 * sn);
}

// ====== gemm_qkv8: 8-phase-style schedule. BM=256, BN=192, BK=64, 512 thr (2x4) ======
// Per K-tile 4 phases: P1{reads A-own m0-3 ks01 + B ks0; bar; 12 MFMA m0-3 ks0}
//                      P2{reads A m4-7 ks01 + B ks1;    bar; 12 MFMA m4-7 ks0}
//  (P2-end barrier == all waves' reads of buf retired -> safe to stage into it)
//                      P3{stage A(kt+2); bar; 12 MFMA m0-3 ks1}
//                      P4{stage B(kt+2); bar; 12 MFMA m4-7 ks1}
// vmcnt(7) once per tile top (retires kt, leaves kt+1's 7 loads in flight);
// vmcnt(0) only at last tile. 3-bit XOR swizzle (verified conflict-free).
// LDS 112 KB -> 1 block/CU; grid 512 = 2 clean rounds; XCD owns 4 B-col-blocks.
__global__ __launch_bounds__(512, 2) void gemm_qkv8(
    const ushort_t* __restrict__ A, const ushort_t* __restrict__ Bm,
    ushort_t* __restrict__ Cq, ushort_t* __restrict__ Ck, ushort_t* __restrict__ Cv,
    int K) {
    __shared__ __align__(16) ushort_t As[2][256 * 64];
    __shared__ __align__(16) ushort_t Bs[2][192 * 64];
    const int tid = threadIdx.x;
    const int lane = tid & 63;
    const int w = tid >> 6;
    const int wm = w >> 2, wn = w & 3;       // 2 x 4 waves, per-wave 128 x 48
    const int fr = lane & 15, g = lane >> 4;
    const int xcd = blockIdx.x & 7;
    const int local = blockIdx.x >> 3;       // 0..63
    const int brow = (local >> 2) * 256;
    const int bcol = (xcd * 4 + (local & 3)) * 192;

    // staging: linear LDS dest, involutive pre-swizzled global source, hoisted bases
    const ushort_t* aSrc[4]; const ushort_t* bSrc[3];
    int aDst[4], bDst[3];
#pragma unroll
    for (int q = 0; q < 4; q++) {
        int d = (q * 512 + tid) * 16;
        int row = d >> 7;
        int s = d ^ ((row & 7) << 4);
        aSrc[q] = A + (long)(brow + row) * K + ((s & 127) >> 1);
        aDst[q] = (q * 512 + tid) * 8;
    }
#pragma unroll
    for (int q = 0; q < 3; q++) {
        int d = (q * 512 + tid) * 16;
        int row = d >> 7;
        int s = d ^ ((row & 7) << 4);
        bSrc[q] = Bm + (long)(bcol + row) * K + ((s & 127) >> 1);
        bDst[q] = (q * 512 + tid) * 8;
    }

    f32x4 acc[8][3];
#pragma unroll
    for (int m = 0; m < 8; m++)
#pragma unroll
        for (int n = 0; n < 3; n++) acc[m][n] = (f32x4){0.f, 0.f, 0.f, 0.f};

    auto stageA = [&](int buf, int k0) {
#pragma unroll
        for (int q = 0; q < 4; q++) async16(aSrc[q] + k0, &As[buf][aDst[q]]);
    };
    auto stageB = [&](int buf, int k0) {
#pragma unroll
        for (int q = 0; q < 3; q++) async16(bSrc[q] + k0, &Bs[buf][bDst[q]]);
    };
    auto rdA = [&](int buf, int m, int ks) -> bf16x8 {
        int row = wm * 128 + m * 16 + fr;
        int cb = (ks * 64 + g * 16) ^ ((row & 7) << 4);
        return *(const bf16x8*)((const char*)&As[buf][0] + row * 128 + cb);
    };
    auto rdB = [&](int buf, int n, int ks) -> bf16x8 {
        int row = wn * 48 + n * 16 + fr;
        int cb = (ks * 64 + g * 16) ^ ((row & 7) << 4);
        return *(const bf16x8*)((const char*)&Bs[buf][0] + row * 128 + cb);
    };

    const int NT = K / 64;                   // 32
    stageA(0, 0);  stageB(0, 0);
    stageA(1, 64); stageB(1, 64);

    for (int kt = 0; kt < NT; ++kt) {
        const int cur = kt & 1;
        // ---- tile top: retire tile kt's loads (leave kt+1's 7 in flight) ----
        __builtin_amdgcn_sched_barrier(0);
        if (kt + 1 < NT) asm volatile("s_waitcnt vmcnt(7)" ::: "memory");
        else             asm volatile("s_waitcnt vmcnt(0)" ::: "memory");
        __builtin_amdgcn_sched_barrier(0);
        __builtin_amdgcn_s_barrier();
        __builtin_amdgcn_sched_barrier(0);

        bf16x8 af0[4][2], af1[4][2], bfv[3][2];
        // ======== P1: reads (A own-half m0-3, both ks; B ks0) + MFMA m0-3 ks0 ========
#pragma unroll
        for (int m = 0; m < 4; m++)
#pragma unroll
            for (int ks = 0; ks < 2; ks++) af0[m][ks] = rdA(cur, m, ks);
#pragma unroll
        for (int n = 0; n < 3; n++) bfv[n][0] = rdB(cur, n, 0);
        __builtin_amdgcn_sched_barrier(0);
        __builtin_amdgcn_s_barrier();
        __builtin_amdgcn_sched_barrier(0);
        __builtin_amdgcn_s_setprio(1);
#pragma unroll
        for (int m = 0; m < 4; m++)
#pragma unroll
            for (int n = 0; n < 3; n++)
                acc[m][n] = __builtin_amdgcn_mfma_f32_16x16x32_bf16(af0[m][0], bfv[n][0], acc[m][n], 0, 0, 0);
        __builtin_amdgcn_s_setprio(0);
        __builtin_amdgcn_sched_barrier(0);
        __builtin_amdgcn_s_barrier();
        __builtin_amdgcn_sched_barrier(0);
        // ======== P2: reads (A m4-7 both ks; B ks1) + MFMA m4-7 ks0 ========
#pragma unroll
        for (int m = 0; m < 4; m++)
#pragma unroll
            for (int ks = 0; ks < 2; ks++) af1[m][ks] = rdA(cur, m + 4, ks);
#pragma unroll
        for (int n = 0; n < 3; n++) bfv[n][1] = rdB(cur, n, 1);
        __builtin_amdgcn_sched_barrier(0);
        __builtin_amdgcn_s_barrier();
        __builtin_amdgcn_sched_barrier(0);
        __builtin_amdgcn_s_setprio(1);
#pragma unroll
        for (int m = 0; m < 4; m++)
#pragma unroll
            for (int n = 0; n < 3; n++)
                acc[m + 4][n] = __builtin_amdgcn_mfma_f32_16x16x32_bf16(af1[m][0], bfv[n][0], acc[m + 4][n], 0, 0, 0);
        __builtin_amdgcn_s_setprio(0);
        __builtin_amdgcn_sched_barrier(0);
        __builtin_amdgcn_s_barrier();   // all waves' buf-cur reads retired past here
        __builtin_amdgcn_sched_barrier(0);
        // ======== P3: stage A(kt+2) into freed buf + MFMA m0-3 ks1 ========
        if (kt + 2 < NT) stageA(cur, (kt + 2) * 64);
        __builtin_amdgcn_sched_barrier(0);
        __builtin_amdgcn_s_barrier();
        __builtin_amdgcn_sched_barrier(0);
        __builtin_amdgcn_s_setprio(1);
#pragma unroll
        for (int m = 0; m < 4; m++)
#pragma unroll
            for (int n = 0; n < 3; n++)
                acc[m][n] = __builtin_amdgcn_mfma_f32_16x16x32_bf16(af0[m][1], bfv[n][1], acc[m][n], 0, 0, 0);
        __builtin_amdgcn_s_setprio(0);
        __builtin_amdgcn_sched_barrier(0);
        __builtin_amdgcn_s_barrier();
        __builtin_amdgcn_sched_barrier(0);
        // ======== P4: stage B(kt+2) + MFMA m4-7 ks1 ========
        if (kt + 2 < NT) stageB(cur, (kt + 2) * 64);
        __builtin_amdgcn_sched_barrier(0);
        __builtin_amdgcn_s_barrier();
        __builtin_amdgcn_sched_barrier(0);
        __builtin_amdgcn_s_setprio(1);
#pragma unroll
        for (int m = 0; m < 4; m++)
#pragma unroll
            for (int n = 0; n < 3; n++)
                acc[m + 4][n] = __builtin_amdgcn_mfma_f32_16x16x32_bf16(af1[m][1], bfv[n][1], acc[m + 4][n], 0, 0, 0);
        __builtin_amdgcn_s_setprio(0);
        __builtin_amdgcn_sched_barrier(0);
    }

    // ---- epilogue: fused [Q|K|V] scatter ----
    const int rbase = brow + wm * 128;
#pragma unroll
    for (int n = 0; n < 3; n++) {
        int c2abs = bcol + wn * 48 + n * 16 + fr;   // [0, 6144)
        int proj = c2abs >> 11;                     // 16-col frag never straddles
        int c2 = c2abs & 2047;
        int h = c2 >> 7, hd = c2 & 127;
        if (proj < 2) {
            ushort_t* dst = proj == 0 ? Cq : Ck;
#pragma unroll
            for (int m = 0; m < 8; m++)
#pragma unroll
                for (int r = 0; r < 4; r++) {
                    int row = rbase + m * 16 + g * 4 + r;
                    int b = row >> 11, s = row & (S_LEN - 1);
                    dst[(((long)(b * NH + h) * S_LEN) + s) * HDIM + hd] = f2bf(acc[m][n][r]);
                }
        } else {
#pragma unroll
            for (int m = 0; m < 8; m++) {
                int row0 = rbase + m * 16 + g * 4;
                int b = row0 >> 11, s0 = row0 & (S_LEN - 1);
                ushort4 u;
                u.x = f2bf(acc[m][n][0]); u.y = f2bf(acc[m][n][1]);
                u.z = f2bf(acc[m][n][2]); u.w = f2bf(acc[m][n][3]);
                *(ushort4*)&Cv[(((long)(b * NH + h) * HDIM) + hd) * S_LEN + s0] = u;
            }
        }
    }
}

// ====== gemm128b (O-proj): BM=128, BN=128, BK=64, 256 threads, 2x2 waves ======
__global__ __launch_bounds__(256) void gemm128_o(
    const ushort_t* __restrict__ A, const ushort_t* __restrict__ Bm,
    float* __restrict__ C0, int NB, int K) {
    __shared__ __align__(16) ushort_t As[2][128 * 64];
    __shared__ __align__(16) ushort_t Bs[2][128 * 64];
    const int tid = threadIdx.x;
    const int lane = tid & 63;
    const int w = tid >> 6;
    const int wm = w >> 1, wn = w & 1;
    const int fr = lane & 15, g = lane >> 4;
    const int cpx = NB >> 3;
    const int xcd = blockIdx.x & 7;
    const int local = blockIdx.x >> 3;
    const int brow = (local / cpx) * 128;
    const int bcol = (xcd * cpx + local % cpx) * 128;

    const ushort_t* aSrc[4]; const ushort_t* bSrc[4];
    int aDst[4], bDst[4];
#pragma unroll
    for (int q = 0; q < 4; q++) {
        int d = (q * 256 + tid) * 16;
        int row = d >> 7;
        int s = d ^ ((row & 7) << 4);
        aSrc[q] = A + (long)(brow + row) * K + ((s & 127) >> 1);
        bSrc[q] = Bm + (long)(bcol + row) * K + ((s & 127) >> 1);
        aDst[q] = bDst[q] = (q * 256 + tid) * 8;
    }

    f32x4 acc[4][4];
#pragma unroll
    for (int m = 0; m < 4; m++)
#pragma unroll
        for (int n = 0; n < 4; n++) acc[m][n] = (f32x4){0.f, 0.f, 0.f, 0.f};

    auto stage = [&](int buf, int k0) {
#pragma unroll
        for (int q = 0; q < 4; q++) async16(aSrc[q] + k0, &As[buf][aDst[q]]);
#pragma unroll
        for (int q = 0; q < 4; q++) async16(bSrc[q] + k0, &Bs[buf][bDst[q]]);
    };
    auto rdA = [&](int buf, int m, int ks) -> bf16x8 {
        int row = wm * 64 + m * 16 + fr;
        int cb = (ks * 64 + g * 16) ^ ((row & 7) << 4);
        return *(const bf16x8*)((const char*)&As[buf][0] + row * 128 + cb);
    };
    auto rdB = [&](int buf, int n, int ks) -> bf16x8 {
        int row = wn * 64 + n * 16 + fr;
        int cb = (ks * 64 + g * 16) ^ ((row & 7) << 4);
        return *(const bf16x8*)((const char*)&Bs[buf][0] + row * 128 + cb);
    };

    const int NT = K / 64;
    stage(0, 0);
    stage(1, 64);

    for (int kt = 0; kt < NT; ++kt) {
        const int cur = kt & 1;
        if (kt + 1 < NT) asm volatile("s_waitcnt vmcnt(8)" ::: "memory");
        else             asm volatile("s_waitcnt vmcnt(0)" ::: "memory");
        __builtin_amdgcn_sched_barrier(0);
        __builtin_amdgcn_s_barrier();
        __builtin_amdgcn_sched_barrier(0);

        bf16x8 bfv[4][2], af[4][2];
#pragma unroll
        for (int n = 0; n < 4; n++)
#pragma unroll
            for (int ks = 0; ks < 2; ks++) bfv[n][ks] = rdB(cur, n, ks);
#pragma unroll
        for (int m = 0; m < 4; m++)
#pragma unroll
            for (int ks = 0; ks < 2; ks++) af[m][ks] = rdA(cur, m, ks);
        __builtin_amdgcn_s_setprio(1);
#pragma unroll
        for (int m = 0; m < 4; m++)
#pragma unroll
            for (int n = 0; n < 4; n++)
#pragma unroll
                for (int ks = 0; ks < 2; ks++)
                    acc[m][n] = __builtin_amdgcn_mfma_f32_16x16x32_bf16(af[m][ks], bfv[n][ks], acc[m][n], 0, 0, 0);
        __builtin_amdgcn_s_setprio(0);

        __builtin_amdgcn_s_barrier();
        __builtin_amdgcn_sched_barrier(0);
        if (kt + 2 < NT) stage(cur, (kt + 2) * 64);
    }

#pragma unroll
    for (int m = 0; m < 4; m++)
#pragma unroll
        for (int n = 0; n < 4; n++) {
            int col = bcol + wn * 64 + n * 16 + fr;
#pragma unroll
            for (int r = 0; r < 4; r++) {
                int row = brow + wm * 64 + m * 16 + g * 4 + r;
                C0[(long)row * DMODEL + col] = acc[m][n][r];
            }
        }
}

// ---------------- Flash attention v4b: R9 structure + base-2 softmax ----------
__global__ __launch_bounds__(256) void attn_fwd_v4(
    const ushort_t* __restrict__ Q, const ushort_t* __restrict__ K,
    const ushort_t* __restrict__ Vt, ushort_t* __restrict__ ctx) {
    __shared__ __align__(16) ushort_t Ks[2][64 * 128];
    __shared__ __align__(16) ushort_t Vs[2][128 * 64];
    __shared__ __align__(16) ushort_t Pls[4][16 * 64];

    const int tid = threadIdx.x;
    const int lane = tid & 63;
    const int w = tid >> 6;
    const int g = lane >> 4;
    const int fr = lane & 15;
    const int fk = g * 8;

    const int bid = blockIdx.x;              // 512 blocks
    const int xcd = bid & 7;
    const int t6 = bid >> 3;                 // 0..63
    const int bh = xcd + 8 * (t6 & 3);       // 4 heads per XCD
    const int p = t6 >> 2;                   // 0..15 pair index
    const int qtA = p, qtB = 31 - p;
    const int b = bh >> 4, h = bh & 15;

    const ushort_t* Qb = Q + (long)bh * S_LEN * HDIM;
    const ushort_t* Kb = K + (long)bh * S_LEN * HDIM;
    const ushort_t* Vb = Vt + (long)bh * HDIM * S_LEN;

    int koff[4], voff[4], kdst[4], vdst[4];
#pragma unroll
    for (int r = 0; r < 4; r++) {
        int ci = r * 256 + tid;
        int krow = ci >> 4, kwc = ci & 15;
        koff[r] = krow * HDIM + ((kwc ^ (krow & 7)) * 8);
        kdst[r] = ci * 8;
        int vrow = ci >> 3, vwc = ci & 7;
        voff[r] = vrow * S_LEN + ((vwc ^ (vrow & 7)) * 8);
        vdst[r] = ci * 8;
    }
    auto stage = [&](int buf, int kv0) {
        const ushort_t* Kg = Kb + (long)kv0 * HDIM;
        const ushort_t* Vg = Vb + kv0;
#pragma unroll
        for (int r = 0; r < 4; r++) async16(Kg + koff[r], &Ks[buf][kdst[r]]);
#pragma unroll
        for (int r = 0; r < 4; r++) async16(Vg + voff[r], &Vs[buf][vdst[r]]);
    };

    int qrow0 = qtA * 64 + w * 16;
    bf16x8 qf[4];
    auto loadQ = [&]() {
#pragma unroll
        for (int t = 0; t < 4; t++)
            qf[t] = *(const bf16x8*)&Qb[(long)(qrow0 + fr) * HDIM + t * 32 + fk];
    };
    loadQ();

    f32x4 o[8];
#pragma unroll
    for (int i = 0; i < 8; i++) o[i] = (f32x4){0.f, 0.f, 0.f, 0.f};
    float mrun = -1e30f, lrun = 0.f;

    const float scale2 = 0.08838834764831845f * 1.4426950408889634f;
    long obase = ((long)b * S_LEN) * DMODEL + (long)h * HDIM;
    auto flush = [&]() {
        float inv = 1.0f / lrun;
        long rowb = obase + (long)(qrow0 + fr) * DMODEL;
#pragma unroll
        for (int dt = 0; dt < 8; dt++) {
            ushort4 u;
            u.x = f2bf(o[dt][0] * inv); u.y = f2bf(o[dt][1] * inv);
            u.z = f2bf(o[dt][2] * inv); u.w = f2bf(o[dt][3] * inv);
            *(ushort4*)&ctx[rowb + dt * 16 + g * 4] = u;
        }
    };

    const int ntA = qtA + 1;
    const int ntot = 33;

    stage(0, 0);
    __syncthreads();

    int cur = 0;
    for (int u = 0; u < ntot; ++u) {
        if (u + 1 < ntot) {
            int kvn = (u + 1 < ntA) ? (u + 1) : (u + 1 - ntA);
            stage(cur ^ 1, kvn * 64);
        }
        const int kv0 = ((u < ntA) ? u : (u - ntA)) * 64;
        if (u == ntA) {
            flush();
            qrow0 = qtB * 64 + w * 16;
            loadQ();
#pragma unroll
            for (int i = 0; i < 8; i++) o[i] = (f32x4){0.f, 0.f, 0.f, 0.f};
            mrun = -1e30f; lrun = 0.f;
        }
        if (kv0 <= qrow0 + 15) {
            f32x4 sf[4];
#pragma unroll
            for (int c = 0; c < 4; c++) sf[c] = (f32x4){0.f, 0.f, 0.f, 0.f};
            __builtin_amdgcn_s_setprio(1);
#pragma unroll
            for (int c = 0; c < 4; c++) {
                const int krow = c * 16 + fr;
#pragma unroll
                for (int tt = 0; tt < 4; tt++) {
                    bf16x8 kb = *(const bf16x8*)&Ks[cur][krow * 128 + (((tt * 4 + g) ^ (krow & 7)) * 8)];
                    sf[c] = __builtin_amdgcn_mfma_f32_16x16x32_bf16(kb, qf[tt], sf[c], 0, 0, 0);
                }
            }
            __builtin_amdgcn_s_setprio(0);
            if (kv0 + 63 <= qrow0) {
#pragma unroll
                for (int c = 0; c < 4; c++)
#pragma unroll
                    for (int r = 0; r < 4; r++) sf[c][r] *= scale2;
            } else {
                const int q = qrow0 + fr;
#pragma unroll
                for (int c = 0; c < 4; c++)
#pragma unroll
                    for (int r = 0; r < 4; r++) {
                        int kv = kv0 + c * 16 + g * 4 + r;
                        sf[c][r] = (kv <= q) ? sf[c][r] * scale2 : -1e30f;
                    }
            }
            {
                float vmax = -1e30f;
#pragma unroll
                for (int c = 0; c < 4; c++) {
                    float t0 = fmaxf(fmaxf(sf[c][0], sf[c][1]), fmaxf(sf[c][2], sf[c][3]));
                    vmax = fmaxf(vmax, t0);
                }
                vmax = fmaxf(vmax, __shfl_xor(vmax, 16));
                vmax = fmaxf(vmax, __shfl_xor(vmax, 32));
                if (!__all(vmax - mrun <= 11.5f)) {
                    float nm = fmaxf(mrun, vmax);
                    float alpha = exp2f(mrun - nm);
                    mrun = nm;
                    lrun *= alpha;
#pragma unroll
                    for (int dt = 0; dt < 8; dt++) o[dt] *= alpha;
                }
                float rs = 0.f;
#pragma unroll
                for (int c = 0; c < 4; c++)
#pragma unroll
                    for (int r = 0; r < 4; r++) {
                        float pv = exp2f(sf[c][r] - mrun);
                        sf[c][r] = pv;
                        rs += pv;
                    }
                rs += __shfl_xor(rs, 16);
                rs += __shfl_xor(rs, 32);
                lrun += rs;
            }
#pragma unroll
            for (int c = 0; c < 4; c++) {
                ushort4 u2;
                u2.x = f2bf(sf[c][0]); u2.y = f2bf(sf[c][1]);
                u2.z = f2bf(sf[c][2]); u2.w = f2bf(sf[c][3]);
                *(ushort4*)&Pls[w][fr * 64 + ((c * 16 + g * 4) ^ ((fr & 7) << 3))] = u2;
            }
            bf16x8 pa[2];
#pragma unroll
            for (int hh = 0; hh < 2; hh++)
                pa[hh] = *(const bf16x8*)&Pls[w][fr * 64 + ((hh * 32 + g * 8) ^ ((fr & 7) << 3))];
            __builtin_amdgcn_s_setprio(1);
#pragma unroll
            for (int dt = 0; dt < 8; dt++) {
                const int vrow = dt * 16 + fr;
#pragma unroll
                for (int hh = 0; hh < 2; hh++) {
                    bf16x8 vb = *(const bf16x8*)&Vs[cur][vrow * 64 + (((hh * 4 + g) ^ (vrow & 7)) * 8)];
                    o[dt] = __builtin_amdgcn_mfma_f32_16x16x32_bf16(vb, pa[hh], o[dt], 0, 0, 0);
                }
            }
            __builtin_amdgcn_s_setprio(0);
        }
        __syncthreads();
        cur ^= 1;
    }
    flush();
}

extern "C" void kernel_launch(void* const* d_in, const int* in_sizes, int n_in,
                              void* d_out, int out_size, void* d_ws, size_t ws_size,
                              hipStream_t stream) {
    const float* hs = (const float*)d_in[0];
    const float* Wq = (const float*)d_in[1];
    const float* Wk = (const float*)d_in[2];
    const float* Wv = (const float*)d_in[3];
    const float* Wo = (const float*)d_in[4];
    float* out = (float*)d_out;

    size_t off = 0;
    char* wsb = (char*)d_ws;
    auto carve = [&](size_t bytes) { void* p = wsb + off; off += bytes; return p; };

    ushort_t* Xb   = (ushort_t*)carve((size_t)M_ROWS * DMODEL * 2);
    ushort_t* Wqb  = (ushort_t*)carve((size_t)DMODEL * DMODEL * 2); // Wq|Wk|Wv|Wo contiguous
    ushort_t* Wkb  = (ushort_t*)carve((size_t)DMODEL * DMODEL * 2);
    ushort_t* Wvb  = (ushort_t*)carve((size_t)DMODEL * DMODEL * 2);
    ushort_t* Wob  = (ushort_t*)carve((size_t)DMODEL * DMODEL * 2);
    ushort_t* Qb   = (ushort_t*)carve((size_t)BATCH * NH * S_LEN * HDIM * 2);
    ushort_t* Kb   = (ushort_t*)carve((size_t)BATCH * NH * S_LEN * HDIM * 2);
    ushort_t* Vtb  = (ushort_t*)carve((size_t)BATCH * NH * S_LEN * HDIM * 2);
    ushort_t* ctxb = (ushort_t*)carve((size_t)M_ROWS * DMODEL * 2);
    float* cosT    = (float*)carve((size_t)S_LEN * 64 * 4);
    float* sinT    = (float*)carve((size_t)S_LEN * 64 * 4);

    const int nX = M_ROWS * DMODEL;   // 8388608
    const int nW = DMODEL * DMODEL;   // 4194304

    cvt_bf16<<<(nX / 4) / 256, 256, 0, stream>>>(hs, Xb, nX / 4);
    cvt4_bf16<<<dim3((nW / 4) / 256, 4), 256, 0, stream>>>(Wq, Wk, Wv, Wo, Wqb, nW / 4);
    rope_tables<<<(S_LEN * 64) / 256, 256, 0, stream>>>(cosT, sinT);

    // Fused QKV projection, 8-phase-style: BM=256, BN=192 -> grid 16x32 = 512 = 2 rounds.
    gemm_qkv8<<<512, 512, 0, stream>>>(Xb, Wqb, Qb, Kb, Vtb, DMODEL);

    rope_inplace<<<(BATCH * NH * S_LEN * 64) / 256, 256, 0, stream>>>(Qb, Kb, cosT, sinT);

    attn_fwd_v4<<<512, 256, 0, stream>>>(Qb, Kb, Vtb, ctxb);

    // Output projection: BM=128, BN=128 -> grid 32 x 16 = 512 blocks = 1 pair-round.
    gemm128_o<<<(M_ROWS / 128) * (DMODEL / 128), 256, 0, stream>>>(
        ctxb, Wob, out, DMODEL / 128, DMODEL);
}

// Round 16
// 257.396 us; speedup vs baseline: 1.0470x; 1.0470x over previous
//
#include <hip/hip_runtime.h>

typedef unsigned short ushort_t;
typedef __bf16 bf16x8 __attribute__((ext_vector_type(8)));
typedef float f32x4 __attribute__((ext_vector_type(4)));

#define S_LEN 2048
#define DMODEL 2048
#define NH 16
#define HDIM 128
#define BATCH 2
#define M_ROWS (BATCH * S_LEN) // 4096

__device__ __forceinline__ ushort_t f2bf(float f) {
    union { float f; unsigned u; } v; v.f = f;
    unsigned r = (v.u + 0x7fffu + ((v.u >> 16) & 1u)) >> 16;
    return (ushort_t)r;
}
__device__ __forceinline__ float bf2f(ushort_t u) {
    union { unsigned u; float f; } v; v.u = ((unsigned)u) << 16;
    return v.f;
}

__device__ __forceinline__ void async16(const void* g, void* l) {
    __builtin_amdgcn_global_load_lds(
        (const __attribute__((address_space(1))) void*)g,
        (__attribute__((address_space(3))) void*)l, 16, 0, 0);
}

// ---------------- fp32 -> bf16 (4 elems/thread) ----------------
__global__ void cvt_bf16(const float* __restrict__ in, ushort_t* __restrict__ out, int n4) {
    int i = blockIdx.x * blockDim.x + threadIdx.x;
    if (i >= n4) return;
    float4 f = ((const float4*)in)[i];
    ushort4 u;
    u.x = f2bf(f.x); u.y = f2bf(f.y); u.z = f2bf(f.z); u.w = f2bf(f.w);
    ((ushort4*)out)[i] = u;
}

// ---------------- fp32 -> bf16 for the 4 weight matrices in one launch ----------
__global__ void cvt4_bf16(const float* __restrict__ w0, const float* __restrict__ w1,
                          const float* __restrict__ w2, const float* __restrict__ w3,
                          ushort_t* __restrict__ out, int n4) {
    int i = blockIdx.x * blockDim.x + threadIdx.x;
    if (i >= n4) return;
    int which = blockIdx.y;
    const float* src = which == 0 ? w0 : which == 1 ? w1 : which == 2 ? w2 : w3;
    float4 f = ((const float4*)src)[i];
    ushort4 u;
    u.x = f2bf(f.x); u.y = f2bf(f.y); u.z = f2bf(f.z); u.w = f2bf(f.w);
    ((ushort4*)(out + (size_t)which * DMODEL * DMODEL))[i] = u;
}

// ---------------- RoPE tables [S][64] ----------------
__global__ void rope_tables(float* __restrict__ cosT, float* __restrict__ sinT) {
    int i = blockIdx.x * blockDim.x + threadIdx.x; // 2048*64
    int s = i >> 6, f = i & 63;
    float inv = powf(10000.0f, -(float)(2 * f) / 128.0f);
    float ang = (float)s * inv;
    cosT[i] = cosf(ang);
    sinT[i] = sinf(ang);
}

// ---------------- RoPE in-place on Q and K ([BH][S][HD] bf16) ----------------
__global__ void rope_inplace(ushort_t* __restrict__ Q, ushort_t* __restrict__ K,
                             const float* __restrict__ cosT, const float* __restrict__ sinT) {
    long i = (long)blockIdx.x * blockDim.x + threadIdx.x; // 32*2048*64
    int f = (int)(i & 63);
    long t = i >> 6;
    int s = (int)(t & (S_LEN - 1));
    int bh = (int)(t >> 11);
    long base = ((long)bh * S_LEN + s) * HDIM;
    float c = cosT[s * 64 + f], sn = sinT[s * 64 + f];
    float a0 = bf2f(Q[base + f]), a1 = bf2f(Q[base + 64 + f]);
    Q[base + f]      = f2bf(a0 * c - a1 * sn);
    Q[base + 64 + f] = f2bf(a1 * c + a0 * sn);
    float b0 = bf2f(K[base + f]), b1 = bf2f(K[base + 64 + f]);
    K[base + f]      = f2bf(b0 * c - b1 * sn);
    K[base + 64 + f] = f2bf(b1 * c + b0 * sn);
}

// ====== gemm128 (R9/R13, verified): BM=128, BN=NF*64, BK=64, 4 waves, 2 blocks/CU ======
template <int EPI, int NF>
__global__ __launch_bounds__(256) void gemm128(
    const ushort_t* __restrict__ A, const ushort_t* __restrict__ Bm,
    void* __restrict__ C0, void* __restrict__ C1, void* __restrict__ C2,
    int NB, int K) {
    __shared__ __align__(16) ushort_t As[2][128 * 64];
    __shared__ __align__(16) ushort_t Bs[2][NF * 64 * 64];
    const int tid = threadIdx.x;
    const int lane = tid & 63;
    const int w = tid >> 6;                 // 0..3 = n-wave
    const int fr = lane & 15, g = lane >> 4;
    const int WN = NF * 16;
    const int BN = NF * 64;
    const int cpx = NB >> 3;
    const int xcd = blockIdx.x & 7;
    const int local = blockIdx.x >> 3;
    const int brow = (local / cpx) * 128;
    const int bcol = (xcd * cpx + local % cpx) * BN;

    int aRow[4], aK[4], bRow[2 * NF], bK[2 * NF];
#pragma unroll
    for (int q = 0; q < 4; q++) {
        int d = (q * 256 + tid) * 16;
        int row = d >> 7;
        int s = d ^ ((row & 7) << 4);
        aRow[q] = row; aK[q] = (s & 127) >> 1;
    }
#pragma unroll
    for (int q = 0; q < 2 * NF; q++) {
        int d = (q * 256 + tid) * 16;
        int row = d >> 7;
        int s = d ^ ((row & 7) << 4);
        bRow[q] = row; bK[q] = (s & 127) >> 1;
    }

    f32x4 acc[8][NF];
#pragma unroll
    for (int m = 0; m < 8; m++)
#pragma unroll
        for (int n = 0; n < NF; n++) acc[m][n] = (f32x4){0.f, 0.f, 0.f, 0.f};

    auto stage = [&](int buf, int k0) {
#pragma unroll
        for (int q = 0; q < 4; q++)
            async16(&A[(long)(brow + aRow[q]) * K + k0 + aK[q]], &As[buf][(q * 256 + tid) * 8]);
#pragma unroll
        for (int q = 0; q < 2 * NF; q++)
            async16(&Bm[(long)(bcol + bRow[q]) * K + k0 + bK[q]], &Bs[buf][(q * 256 + tid) * 8]);
    };
    auto rdA = [&](int buf, int m, int ks) -> bf16x8 {
        int row = m * 16 + fr;
        int cb = (ks * 64 + g * 16) ^ ((row & 7) << 4);
        return *(const bf16x8*)((const char*)&As[buf][0] + row * 128 + cb);
    };
    auto rdB = [&](int buf, int n, int ks) -> bf16x8 {
        int row = w * WN + n * 16 + fr;
        int cb = (ks * 64 + g * 16) ^ ((row & 7) << 4);
        return *(const bf16x8*)((const char*)&Bs[buf][0] + row * 128 + cb);
    };

    const int NT = K / 64;
    stage(0, 0);
    stage(1, 64);

    for (int kt = 0; kt < NT; ++kt) {
        const int cur = kt & 1;
        if (kt + 1 < NT) {
            if constexpr (NF == 2)      asm volatile("s_waitcnt vmcnt(8)" ::: "memory");
            else                        asm volatile("s_waitcnt vmcnt(10)" ::: "memory");
        } else {
            asm volatile("s_waitcnt vmcnt(0)" ::: "memory");
        }
        __builtin_amdgcn_sched_barrier(0);
        __builtin_amdgcn_s_barrier();
        __builtin_amdgcn_sched_barrier(0);

        bf16x8 bfv[NF][2], af[8][2];
#pragma unroll
        for (int n = 0; n < NF; n++)
#pragma unroll
            for (int ks = 0; ks < 2; ks++) bfv[n][ks] = rdB(cur, n, ks);
#pragma unroll
        for (int m = 0; m < 8; m++)
#pragma unroll
            for (int ks = 0; ks < 2; ks++) af[m][ks] = rdA(cur, m, ks);
        __builtin_amdgcn_s_setprio(1);
#pragma unroll
        for (int m = 0; m < 8; m++)
#pragma unroll
            for (int n = 0; n < NF; n++)
#pragma unroll
                for (int ks = 0; ks < 2; ks++)
                    acc[m][n] = __builtin_amdgcn_mfma_f32_16x16x32_bf16(af[m][ks], bfv[n][ks], acc[m][n], 0, 0, 0);
        __builtin_amdgcn_s_setprio(0);

        __builtin_amdgcn_s_barrier();
        __builtin_amdgcn_sched_barrier(0);
        if (kt + 2 < NT) stage(cur, (kt + 2) * 64);
    }

    if constexpr (EPI == 0) {
#pragma unroll
        for (int n = 0; n < NF; n++) {
            int c2abs = bcol + w * WN + n * 16 + fr;    // [0, 6144)
            int proj = c2abs >> 11;
            int c2 = c2abs & 2047;
            int h = c2 >> 7, hd = c2 & 127;
            if (proj < 2) {
                ushort_t* dst = (ushort_t*)(proj == 0 ? C0 : C1);
#pragma unroll
                for (int m = 0; m < 8; m++)
#pragma unroll
                    for (int r = 0; r < 4; r++) {
                        int row = brow + m * 16 + g * 4 + r;
                        int b = row >> 11, s = row & (S_LEN - 1);
                        dst[(((long)(b * NH + h) * S_LEN) + s) * HDIM + hd] = f2bf(acc[m][n][r]);
                    }
            } else {
                ushort_t* dst = (ushort_t*)C2;
#pragma unroll
                for (int m = 0; m < 8; m++) {
                    int row0 = brow + m * 16 + g * 4;
                    int b = row0 >> 11, s0 = row0 & (S_LEN - 1);
                    ushort4 u;
                    u.x = f2bf(acc[m][n][0]); u.y = f2bf(acc[m][n][1]);
                    u.z = f2bf(acc[m][n][2]); u.w = f2bf(acc[m][n][3]);
                    *(ushort4*)&dst[(((long)(b * NH + h) * HDIM) + hd) * S_LEN + s0] = u;
                }
            }
        }
    } else {
        float* dst = (float*)C0;
#pragma unroll
        for (int m = 0; m < 8; m++)
#pragma unroll
            for (int n = 0; n < NF; n++) {
                int col = bcol + w * WN + n * 16 + fr;
#pragma unroll
                for (int r = 0; r < 4; r++) {
                    int row = brow + m * 16 + g * 4 + r;
                    dst[(long)row * DMODEL + col] = acc[m][n][r];
                }
            }
    }
}

// ---------------- Flash attention v6: single-buffered K/V, 4 blocks/CU ----------
// R13 v4 structure with the double-buffer dropped: LDS 72 -> 40 KB => 4 blocks/CU
// (16 waves/CU at 88 VGPR). Stage latency hidden by inter-block TLP (m114 mechanism,
// the same lever that worked R8->R9) instead of intra-block prefetch.
// Per tile: stage -> __syncthreads (drains vmcnt) -> compute -> __syncthreads.
__global__ __launch_bounds__(256, 4) void attn_fwd_v6(
    const ushort_t* __restrict__ Q, const ushort_t* __restrict__ K,
    const ushort_t* __restrict__ Vt, ushort_t* __restrict__ ctx) {
    __shared__ __align__(16) ushort_t Ks[64 * 128];
    __shared__ __align__(16) ushort_t Vs[128 * 64];
    __shared__ __align__(16) ushort_t Pls[4][16 * 64];

    const int tid = threadIdx.x;
    const int lane = tid & 63;
    const int w = tid >> 6;
    const int g = lane >> 4;
    const int fr = lane & 15;
    const int fk = g * 8;

    const int bid = blockIdx.x;              // 512 blocks
    const int xcd = bid & 7;
    const int t6 = bid >> 3;                 // 0..63
    const int bh = xcd + 8 * (t6 & 3);       // 4 heads per XCD
    const int p = t6 >> 2;                   // 0..15 pair index
    const int qtA = p, qtB = 31 - p;
    const int b = bh >> 4, h = bh & 15;

    const ushort_t* Qb = Q + (long)bh * S_LEN * HDIM;
    const ushort_t* Kb = K + (long)bh * S_LEN * HDIM;
    const ushort_t* Vb = Vt + (long)bh * HDIM * S_LEN;

    int koff[4], voff[4], kdst[4], vdst[4];
#pragma unroll
    for (int r = 0; r < 4; r++) {
        int ci = r * 256 + tid;
        int krow = ci >> 4, kwc = ci & 15;
        koff[r] = krow * HDIM + ((kwc ^ (krow & 7)) * 8);
        kdst[r] = ci * 8;
        int vrow = ci >> 3, vwc = ci & 7;
        voff[r] = vrow * S_LEN + ((vwc ^ (vrow & 7)) * 8);
        vdst[r] = ci * 8;
    }
    auto stage = [&](int kv0) {
        const ushort_t* Kg = Kb + (long)kv0 * HDIM;
        const ushort_t* Vg = Vb + kv0;
#pragma unroll
        for (int r = 0; r < 4; r++) async16(Kg + koff[r], &Ks[kdst[r]]);
#pragma unroll
        for (int r = 0; r < 4; r++) async16(Vg + voff[r], &Vs[vdst[r]]);
    };

    int qrow0 = qtA * 64 + w * 16;
    bf16x8 qf[4];
    auto loadQ = [&]() {
#pragma unroll
        for (int t = 0; t < 4; t++)
            qf[t] = *(const bf16x8*)&Qb[(long)(qrow0 + fr) * HDIM + t * 32 + fk];
    };
    loadQ();

    f32x4 o[8];
#pragma unroll
    for (int i = 0; i < 8; i++) o[i] = (f32x4){0.f, 0.f, 0.f, 0.f};
    float mrun = -1e30f, lrun = 0.f;

    const float scale2 = 0.08838834764831845f * 1.4426950408889634f;
    long obase = ((long)b * S_LEN) * DMODEL + (long)h * HDIM;
    auto flush = [&]() {
        float inv = 1.0f / lrun;
        long rowb = obase + (long)(qrow0 + fr) * DMODEL;
#pragma unroll
        for (int dt = 0; dt < 8; dt++) {
            ushort4 u;
            u.x = f2bf(o[dt][0] * inv); u.y = f2bf(o[dt][1] * inv);
            u.z = f2bf(o[dt][2] * inv); u.w = f2bf(o[dt][3] * inv);
            *(ushort4*)&ctx[rowb + dt * 16 + g * 4] = u;
        }
    };

    const int ntA = qtA + 1;
    const int ntot = 33; // every block does exactly 33 KV-tile units

    for (int u = 0; u < ntot; ++u) {
        const int kv0 = ((u < ntA) ? u : (u - ntA)) * 64;
        if (u == ntA) { // phase switch A -> B
            flush();
            qrow0 = qtB * 64 + w * 16;
            loadQ();
#pragma unroll
            for (int i = 0; i < 8; i++) o[i] = (f32x4){0.f, 0.f, 0.f, 0.f};
            mrun = -1e30f; lrun = 0.f;
        }
        stage(kv0);
        __syncthreads();          // drains vmcnt(0): staged tile visible to all
        if (kv0 <= qrow0 + 15) {
            // ---- QK^T (swapped: A=K rows=kv, B=Q cols=q) ----
            f32x4 sf[4]; // [c]: kv = kv0+c*16+g*4+r, q = qrow0+fr
#pragma unroll
            for (int c = 0; c < 4; c++) sf[c] = (f32x4){0.f, 0.f, 0.f, 0.f};
            __builtin_amdgcn_s_setprio(1);
#pragma unroll
            for (int c = 0; c < 4; c++) {
                const int krow = c * 16 + fr;
#pragma unroll
                for (int tt = 0; tt < 4; tt++) {
                    bf16x8 kb = *(const bf16x8*)&Ks[krow * 128 + (((tt * 4 + g) ^ (krow & 7)) * 8)];
                    sf[c] = __builtin_amdgcn_mfma_f32_16x16x32_bf16(kb, qf[tt], sf[c], 0, 0, 0);
                }
            }
            __builtin_amdgcn_s_setprio(0);
            // ---- scale (base-2) + causal mask ----
            if (kv0 + 63 <= qrow0) {
#pragma unroll
                for (int c = 0; c < 4; c++)
#pragma unroll
                    for (int r = 0; r < 4; r++) sf[c][r] *= scale2;
            } else {
                const int q = qrow0 + fr;
#pragma unroll
                for (int c = 0; c < 4; c++)
#pragma unroll
                    for (int r = 0; r < 4; r++) {
                        int kv = kv0 + c * 16 + g * 4 + r;
                        sf[c][r] = (kv <= q) ? sf[c][r] * scale2 : -1e30f;
                    }
            }
            // ---- online softmax in base-2 (lane owns 16 kv of its q-row) ----
            {
                float vmax = -1e30f;
#pragma unroll
                for (int c = 0; c < 4; c++) {
                    float t0 = fmaxf(fmaxf(sf[c][0], sf[c][1]), fmaxf(sf[c][2], sf[c][3]));
                    vmax = fmaxf(vmax, t0);
                }
                vmax = fmaxf(vmax, __shfl_xor(vmax, 16));
                vmax = fmaxf(vmax, __shfl_xor(vmax, 32));
                if (!__all(vmax - mrun <= 11.5f)) { // defer-max (11.5 bits ~ 8 nats)
                    float nm = fmaxf(mrun, vmax);
                    float alpha = exp2f(mrun - nm);
                    mrun = nm;
                    lrun *= alpha;
#pragma unroll
                    for (int dt = 0; dt < 8; dt++) o[dt] *= alpha;
                }
                float rs = 0.f;
#pragma unroll
                for (int c = 0; c < 4; c++)
#pragma unroll
                    for (int r = 0; r < 4; r++) {
                        float pv = exp2f(sf[c][r] - mrun);
                        sf[c][r] = pv;
                        rs += pv;
                    }
                rs += __shfl_xor(rs, 16);
                rs += __shfl_xor(rs, 32);
                lrun += rs;
            }
            // ---- P -> LDS [q=16][kv=64], b64-packed, XOR-swizzled ----
#pragma unroll
            for (int c = 0; c < 4; c++) {
                ushort4 u2;
                u2.x = f2bf(sf[c][0]); u2.y = f2bf(sf[c][1]);
                u2.z = f2bf(sf[c][2]); u2.w = f2bf(sf[c][3]);
                *(ushort4*)&Pls[w][fr * 64 + ((c * 16 + g * 4) ^ ((fr & 7) << 3))] = u2;
            }
            bf16x8 pa[2]; // B-frag: P[kv=hh*32+g*8+j][q=fr]
#pragma unroll
            for (int hh = 0; hh < 2; hh++)
                pa[hh] = *(const bf16x8*)&Pls[w][fr * 64 + ((hh * 32 + g * 8) ^ ((fr & 7) << 3))];
            // ---- PV: o = mfma(A=V^T rows=d, B=P cols=q) ----
            __builtin_amdgcn_s_setprio(1);
#pragma unroll
            for (int dt = 0; dt < 8; dt++) {
                const int vrow = dt * 16 + fr;
#pragma unroll
                for (int hh = 0; hh < 2; hh++) {
                    bf16x8 vb = *(const bf16x8*)&Vs[vrow * 64 + (((hh * 4 + g) ^ (vrow & 7)) * 8)];
                    o[dt] = __builtin_amdgcn_mfma_f32_16x16x32_bf16(vb, pa[hh], o[dt], 0, 0, 0);
                }
            }
            __builtin_amdgcn_s_setprio(0);
        }
        __syncthreads();          // all reads of Ks/Vs done before next stage
    }
    flush();
}

extern "C" void kernel_launch(void* const* d_in, const int* in_sizes, int n_in,
                              void* d_out, int out_size, void* d_ws, size_t ws_size,
                              hipStream_t stream) {
    const float* hs = (const float*)d_in[0];
    const float* Wq = (const float*)d_in[1];
    const float* Wk = (const float*)d_in[2];
    const float* Wv = (const float*)d_in[3];
    const float* Wo = (const float*)d_in[4];
    float* out = (float*)d_out;

    size_t off = 0;
    char* wsb = (char*)d_ws;
    auto carve = [&](size_t bytes) { void* p = wsb + off; off += bytes; return p; };

    ushort_t* Xb   = (ushort_t*)carve((size_t)M_ROWS * DMODEL * 2);
    ushort_t* Wqb  = (ushort_t*)carve((size_t)DMODEL * DMODEL * 2); // Wq|Wk|Wv|Wo contiguous
    ushort_t* Wkb  = (ushort_t*)carve((size_t)DMODEL * DMODEL * 2);
    ushort_t* Wvb  = (ushort_t*)carve((size_t)DMODEL * DMODEL * 2);
    ushort_t* Wob  = (ushort_t*)carve((size_t)DMODEL * DMODEL * 2);
    ushort_t* Qb   = (ushort_t*)carve((size_t)BATCH * NH * S_LEN * HDIM * 2);
    ushort_t* Kb   = (ushort_t*)carve((size_t)BATCH * NH * S_LEN * HDIM * 2);
    ushort_t* Vtb  = (ushort_t*)carve((size_t)BATCH * NH * S_LEN * HDIM * 2);
    ushort_t* ctxb = (ushort_t*)carve((size_t)M_ROWS * DMODEL * 2);
    float* cosT    = (float*)carve((size_t)S_LEN * 64 * 4);
    float* sinT    = (float*)carve((size_t)S_LEN * 64 * 4);

    const int nX = M_ROWS * DMODEL;   // 8388608
    const int nW = DMODEL * DMODEL;   // 4194304

    cvt_bf16<<<(nX / 4) / 256, 256, 0, stream>>>(hs, Xb, nX / 4);
    cvt4_bf16<<<dim3((nW / 4) / 256, 4), 256, 0, stream>>>(Wq, Wk, Wv, Wo, Wqb, nW / 4);
    rope_tables<<<(S_LEN * 64) / 256, 256, 0, stream>>>(cosT, sinT);

    // Fused QKV projection: A = Xb [4096][2048], B = Wqb..Wvb as [6144][2048].
    gemm128<0, 3><<<(M_ROWS / 128) * (3 * DMODEL / 192), 256, 0, stream>>>(
        Xb, Wqb, Qb, Kb, Vtb, 3 * DMODEL / 192, DMODEL);

    rope_inplace<<<(BATCH * NH * S_LEN * 64) / 256, 256, 0, stream>>>(Qb, Kb, cosT, sinT);

    attn_fwd_v6<<<512, 256, 0, stream>>>(Qb, Kb, Vtb, ctxb);

    // Output projection: BM=128, BN=128 -> grid 32 x 16 = 512 blocks = 1 pair-round.
    gemm128<2, 2><<<(M_ROWS / 128) * (DMODEL / 128), 256, 0, stream>>>(
        ctxb, Wob, out, nullptr, nullptr, DMODEL / 128, DMODEL);
}

// Round 17
// 256.931 us; speedup vs baseline: 1.0489x; 1.0018x over previous
//
#include <hip/hip_runtime.h>

typedef unsigned short ushort_t;
typedef __bf16 bf16x8 __attribute__((ext_vector_type(8)));
typedef float f32x4 __attribute__((ext_vector_type(4)));

#define S_LEN 2048
#define DMODEL 2048
#define NH 16
#define HDIM 128
#define BATCH 2
#define M_ROWS (BATCH * S_LEN) // 4096

__device__ __forceinline__ ushort_t f2bf(float f) {
    union { float f; unsigned u; } v; v.f = f;
    unsigned r = (v.u + 0x7fffu + ((v.u >> 16) & 1u)) >> 16;
    return (ushort_t)r;
}
__device__ __forceinline__ float bf2f(ushort_t u) {
    union { unsigned u; float f; } v; v.u = ((unsigned)u) << 16;
    return v.f;
}

__device__ __forceinline__ void async16(const void* g, void* l) {
    __builtin_amdgcn_global_load_lds(
        (const __attribute__((address_space(1))) void*)g,
        (__attribute__((address_space(3))) void*)l, 16, 0, 0);
}

// ---------------- fp32 -> bf16 (4 elems/thread) ----------------
__global__ void cvt_bf16(const float* __restrict__ in, ushort_t* __restrict__ out, int n4) {
    int i = blockIdx.x * blockDim.x + threadIdx.x;
    if (i >= n4) return;
    float4 f = ((const float4*)in)[i];
    ushort4 u;
    u.x = f2bf(f.x); u.y = f2bf(f.y); u.z = f2bf(f.z); u.w = f2bf(f.w);
    ((ushort4*)out)[i] = u;
}

// ---------------- fp32 -> bf16 for the 4 weight matrices in one launch ----------
__global__ void cvt4_bf16(const float* __restrict__ w0, const float* __restrict__ w1,
                          const float* __restrict__ w2, const float* __restrict__ w3,
                          ushort_t* __restrict__ out, int n4) {
    int i = blockIdx.x * blockDim.x + threadIdx.x;
    if (i >= n4) return;
    int which = blockIdx.y;
    const float* src = which == 0 ? w0 : which == 1 ? w1 : which == 2 ? w2 : w3;
    float4 f = ((const float4*)src)[i];
    ushort4 u;
    u.x = f2bf(f.x); u.y = f2bf(f.y); u.z = f2bf(f.z); u.w = f2bf(f.w);
    ((ushort4*)(out + (size_t)which * DMODEL * DMODEL))[i] = u;
}

// ---------------- RoPE tables [S][64] ----------------
__global__ void rope_tables(float* __restrict__ cosT, float* __restrict__ sinT) {
    int i = blockIdx.x * blockDim.x + threadIdx.x; // 2048*64
    int s = i >> 6, f = i & 63;
    float inv = powf(10000.0f, -(float)(2 * f) / 128.0f);
    float ang = (float)s * inv;
    cosT[i] = cosf(ang);
    sinT[i] = sinf(ang);
}

// ---------------- RoPE in-place, vectorized (G13): 8 threads/row, bf16x8 ----------
// Each thread rotates 8 contiguous (f, f+64) pairs of one Q row and one K row:
// 4 x 16B loads + 4 x 16B stores + 4 x float4 table reads, fully coalesced.
__global__ void rope_inplace_v2(ushort_t* __restrict__ Q, ushort_t* __restrict__ K,
                                const float* __restrict__ cosT, const float* __restrict__ sinT) {
    int i = blockIdx.x * blockDim.x + threadIdx.x;  // 65536 rows * 8
    int sub = i & 7;
    int row = i >> 3;                               // bh*2048 + s
    int s = row & (S_LEN - 1);
    int f0 = sub * 8;
    long base = (long)row * HDIM;

    f32x4 c0 = *(const f32x4*)&cosT[s * 64 + f0];
    f32x4 c1 = *(const f32x4*)&cosT[s * 64 + f0 + 4];
    f32x4 s0 = *(const f32x4*)&sinT[s * 64 + f0];
    f32x4 s1 = *(const f32x4*)&sinT[s * 64 + f0 + 4];

    bf16x8 qlo = *(const bf16x8*)&Q[base + f0];
    bf16x8 qhi = *(const bf16x8*)&Q[base + 64 + f0];
    bf16x8 klo = *(const bf16x8*)&K[base + f0];
    bf16x8 khi = *(const bf16x8*)&K[base + 64 + f0];

    bf16x8 qlo_o, qhi_o, klo_o, khi_o;
#pragma unroll
    for (int j = 0; j < 8; j++) {
        float c = (j < 4) ? c0[j & 3] : c1[j & 3];
        float sn = (j < 4) ? s0[j & 3] : s1[j & 3];
        float ql = (float)qlo[j], qh = (float)qhi[j];
        float kl = (float)klo[j], kh = (float)khi[j];
        qlo_o[j] = (__bf16)(ql * c - qh * sn);
        qhi_o[j] = (__bf16)(qh * c + ql * sn);
        klo_o[j] = (__bf16)(kl * c - kh * sn);
        khi_o[j] = (__bf16)(kh * c + kl * sn);
    }
    *(bf16x8*)&Q[base + f0]      = qlo_o;
    *(bf16x8*)&Q[base + 64 + f0] = qhi_o;
    *(bf16x8*)&K[base + f0]      = klo_o;
    *(bf16x8*)&K[base + 64 + f0] = khi_o;
}

// ====== gemm128 (R9/R13, verified): BM=128, BN=NF*64, BK=64, 4 waves, 2 blocks/CU ======
template <int EPI, int NF>
__global__ __launch_bounds__(256) void gemm128(
    const ushort_t* __restrict__ A, const ushort_t* __restrict__ Bm,
    void* __restrict__ C0, void* __restrict__ C1, void* __restrict__ C2,
    int NB, int K) {
    __shared__ __align__(16) ushort_t As[2][128 * 64];
    __shared__ __align__(16) ushort_t Bs[2][NF * 64 * 64];
    const int tid = threadIdx.x;
    const int lane = tid & 63;
    const int w = tid >> 6;                 // 0..3 = n-wave
    const int fr = lane & 15, g = lane >> 4;
    const int WN = NF * 16;
    const int BN = NF * 64;
    const int cpx = NB >> 3;
    const int xcd = blockIdx.x & 7;
    const int local = blockIdx.x >> 3;
    const int brow = (local / cpx) * 128;
    const int bcol = (xcd * cpx + local % cpx) * BN;

    int aRow[4], aK[4], bRow[2 * NF], bK[2 * NF];
#pragma unroll
    for (int q = 0; q < 4; q++) {
        int d = (q * 256 + tid) * 16;
        int row = d >> 7;
        int s = d ^ ((row & 7) << 4);
        aRow[q] = row; aK[q] = (s & 127) >> 1;
    }
#pragma unroll
    for (int q = 0; q < 2 * NF; q++) {
        int d = (q * 256 + tid) * 16;
        int row = d >> 7;
        int s = d ^ ((row & 7) << 4);
        bRow[q] = row; bK[q] = (s & 127) >> 1;
    }

    f32x4 acc[8][NF];
#pragma unroll
    for (int m = 0; m < 8; m++)
#pragma unroll
        for (int n = 0; n < NF; n++) acc[m][n] = (f32x4){0.f, 0.f, 0.f, 0.f};

    auto stage = [&](int buf, int k0) {
#pragma unroll
        for (int q = 0; q < 4; q++)
            async16(&A[(long)(brow + aRow[q]) * K + k0 + aK[q]], &As[buf][(q * 256 + tid) * 8]);
#pragma unroll
        for (int q = 0; q < 2 * NF; q++)
            async16(&Bm[(long)(bcol + bRow[q]) * K + k0 + bK[q]], &Bs[buf][(q * 256 + tid) * 8]);
    };
    auto rdA = [&](int buf, int m, int ks) -> bf16x8 {
        int row = m * 16 + fr;
        int cb = (ks * 64 + g * 16) ^ ((row & 7) << 4);
        return *(const bf16x8*)((const char*)&As[buf][0] + row * 128 + cb);
    };
    auto rdB = [&](int buf, int n, int ks) -> bf16x8 {
        int row = w * WN + n * 16 + fr;
        int cb = (ks * 64 + g * 16) ^ ((row & 7) << 4);
        return *(const bf16x8*)((const char*)&Bs[buf][0] + row * 128 + cb);
    };

    const int NT = K / 64;
    stage(0, 0);
    stage(1, 64);

    for (int kt = 0; kt < NT; ++kt) {
        const int cur = kt & 1;
        if (kt + 1 < NT) {
            if constexpr (NF == 2)      asm volatile("s_waitcnt vmcnt(8)" ::: "memory");
            else                        asm volatile("s_waitcnt vmcnt(10)" ::: "memory");
        } else {
            asm volatile("s_waitcnt vmcnt(0)" ::: "memory");
        }
        __builtin_amdgcn_sched_barrier(0);
        __builtin_amdgcn_s_barrier();
        __builtin_amdgcn_sched_barrier(0);

        bf16x8 bfv[NF][2], af[8][2];
#pragma unroll
        for (int n = 0; n < NF; n++)
#pragma unroll
            for (int ks = 0; ks < 2; ks++) bfv[n][ks] = rdB(cur, n, ks);
#pragma unroll
        for (int m = 0; m < 8; m++)
#pragma unroll
            for (int ks = 0; ks < 2; ks++) af[m][ks] = rdA(cur, m, ks);
        __builtin_amdgcn_s_setprio(1);
#pragma unroll
        for (int m = 0; m < 8; m++)
#pragma unroll
            for (int n = 0; n < NF; n++)
#pragma unroll
                for (int ks = 0; ks < 2; ks++)
                    acc[m][n] = __builtin_amdgcn_mfma_f32_16x16x32_bf16(af[m][ks], bfv[n][ks], acc[m][n], 0, 0, 0);
        __builtin_amdgcn_s_setprio(0);

        __builtin_amdgcn_s_barrier();
        __builtin_amdgcn_sched_barrier(0);
        if (kt + 2 < NT) stage(cur, (kt + 2) * 64);
    }

    if constexpr (EPI == 0) {
#pragma unroll
        for (int n = 0; n < NF; n++) {
            int c2abs = bcol + w * WN + n * 16 + fr;    // [0, 6144)
            int proj = c2abs >> 11;
            int c2 = c2abs & 2047;
            int h = c2 >> 7, hd = c2 & 127;
            if (proj < 2) {
                ushort_t* dst = (ushort_t*)(proj == 0 ? C0 : C1);
#pragma unroll
                for (int m = 0; m < 8; m++)
#pragma unroll
                    for (int r = 0; r < 4; r++) {
                        int row = brow + m * 16 + g * 4 + r;
                        int b = row >> 11, s = row & (S_LEN - 1);
                        dst[(((long)(b * NH + h) * S_LEN) + s) * HDIM + hd] = f2bf(acc[m][n][r]);
                    }
            } else {
                ushort_t* dst = (ushort_t*)C2;
#pragma unroll
                for (int m = 0; m < 8; m++) {
                    int row0 = brow + m * 16 + g * 4;
                    int b = row0 >> 11, s0 = row0 & (S_LEN - 1);
                    ushort4 u;
                    u.x = f2bf(acc[m][n][0]); u.y = f2bf(acc[m][n][1]);
                    u.z = f2bf(acc[m][n][2]); u.w = f2bf(acc[m][n][3]);
                    *(ushort4*)&dst[(((long)(b * NH + h) * HDIM) + hd) * S_LEN + s0] = u;
                }
            }
        }
    } else {
        float* dst = (float*)C0;
#pragma unroll
        for (int m = 0; m < 8; m++)
#pragma unroll
            for (int n = 0; n < NF; n++) {
                int col = bcol + w * WN + n * 16 + fr;
#pragma unroll
                for (int r = 0; r < 4; r++) {
                    int row = brow + m * 16 + g * 4 + r;
                    dst[(long)row * DMODEL + col] = acc[m][n][r];
                }
            }
    }
}

// ---------------- Flash attention v6: single-buffered K/V, 4 blocks/CU (R16) ----------
__global__ __launch_bounds__(256, 4) void attn_fwd_v6(
    const ushort_t* __restrict__ Q, const ushort_t* __restrict__ K,
    const ushort_t* __restrict__ Vt, ushort_t* __restrict__ ctx) {
    __shared__ __align__(16) ushort_t Ks[64 * 128];
    __shared__ __align__(16) ushort_t Vs[128 * 64];
    __shared__ __align__(16) ushort_t Pls[4][16 * 64];

    const int tid = threadIdx.x;
    const int lane = tid & 63;
    const int w = tid >> 6;
    const int g = lane >> 4;
    const int fr = lane & 15;
    const int fk = g * 8;

    const int bid = blockIdx.x;              // 512 blocks
    const int xcd = bid & 7;
    const int t6 = bid >> 3;                 // 0..63
    const int bh = xcd + 8 * (t6 & 3);       // 4 heads per XCD
    const int p = t6 >> 2;                   // 0..15 pair index
    const int qtA = p, qtB = 31 - p;
    const int b = bh >> 4, h = bh & 15;

    const ushort_t* Qb = Q + (long)bh * S_LEN * HDIM;
    const ushort_t* Kb = K + (long)bh * S_LEN * HDIM;
    const ushort_t* Vb = Vt + (long)bh * HDIM * S_LEN;

    int koff[4], voff[4], kdst[4], vdst[4];
#pragma unroll
    for (int r = 0; r < 4; r++) {
        int ci = r * 256 + tid;
        int krow = ci >> 4, kwc = ci & 15;
        koff[r] = krow * HDIM + ((kwc ^ (krow & 7)) * 8);
        kdst[r] = ci * 8;
        int vrow = ci >> 3, vwc = ci & 7;
        voff[r] = vrow * S_LEN + ((vwc ^ (vrow & 7)) * 8);
        vdst[r] = ci * 8;
    }
    auto stage = [&](int kv0) {
        const ushort_t* Kg = Kb + (long)kv0 * HDIM;
        const ushort_t* Vg = Vb + kv0;
#pragma unroll
        for (int r = 0; r < 4; r++) async16(Kg + koff[r], &Ks[kdst[r]]);
#pragma unroll
        for (int r = 0; r < 4; r++) async16(Vg + voff[r], &Vs[vdst[r]]);
    };

    int qrow0 = qtA * 64 + w * 16;
    bf16x8 qf[4];
    auto loadQ = [&]() {
#pragma unroll
        for (int t = 0; t < 4; t++)
            qf[t] = *(const bf16x8*)&Qb[(long)(qrow0 + fr) * HDIM + t * 32 + fk];
    };
    loadQ();

    f32x4 o[8];
#pragma unroll
    for (int i = 0; i < 8; i++) o[i] = (f32x4){0.f, 0.f, 0.f, 0.f};
    float mrun = -1e30f, lrun = 0.f;

    const float scale2 = 0.08838834764831845f * 1.4426950408889634f;
    long obase = ((long)b * S_LEN) * DMODEL + (long)h * HDIM;
    auto flush = [&]() {
        float inv = 1.0f / lrun;
        long rowb = obase + (long)(qrow0 + fr) * DMODEL;
#pragma unroll
        for (int dt = 0; dt < 8; dt++) {
            ushort4 u;
            u.x = f2bf(o[dt][0] * inv); u.y = f2bf(o[dt][1] * inv);
            u.z = f2bf(o[dt][2] * inv); u.w = f2bf(o[dt][3] * inv);
            *(ushort4*)&ctx[rowb + dt * 16 + g * 4] = u;
        }
    };

    const int ntA = qtA + 1;
    const int ntot = 33;

    for (int u = 0; u < ntot; ++u) {
        const int kv0 = ((u < ntA) ? u : (u - ntA)) * 64;
        if (u == ntA) {
            flush();
            qrow0 = qtB * 64 + w * 16;
            loadQ();
#pragma unroll
            for (int i = 0; i < 8; i++) o[i] = (f32x4){0.f, 0.f, 0.f, 0.f};
            mrun = -1e30f; lrun = 0.f;
        }
        stage(kv0);
        __syncthreads();
        if (kv0 <= qrow0 + 15) {
            f32x4 sf[4];
#pragma unroll
            for (int c = 0; c < 4; c++) sf[c] = (f32x4){0.f, 0.f, 0.f, 0.f};
            __builtin_amdgcn_s_setprio(1);
#pragma unroll
            for (int c = 0; c < 4; c++) {
                const int krow = c * 16 + fr;
#pragma unroll
                for (int tt = 0; tt < 4; tt++) {
                    bf16x8 kb = *(const bf16x8*)&Ks[krow * 128 + (((tt * 4 + g) ^ (krow & 7)) * 8)];
                    sf[c] = __builtin_amdgcn_mfma_f32_16x16x32_bf16(kb, qf[tt], sf[c], 0, 0, 0);
                }
            }
            __builtin_amdgcn_s_setprio(0);
            if (kv0 + 63 <= qrow0) {
#pragma unroll
                for (int c = 0; c < 4; c++)
#pragma unroll
                    for (int r = 0; r < 4; r++) sf[c][r] *= scale2;
            } else {
                const int q = qrow0 + fr;
#pragma unroll
                for (int c = 0; c < 4; c++)
#pragma unroll
                    for (int r = 0; r < 4; r++) {
                        int kv = kv0 + c * 16 + g * 4 + r;
                        sf[c][r] = (kv <= q) ? sf[c][r] * scale2 : -1e30f;
                    }
            }
            {
                float vmax = -1e30f;
#pragma unroll
                for (int c = 0; c < 4; c++) {
                    float t0 = fmaxf(fmaxf(sf[c][0], sf[c][1]), fmaxf(sf[c][2], sf[c][3]));
                    vmax = fmaxf(vmax, t0);
                }
                vmax = fmaxf(vmax, __shfl_xor(vmax, 16));
                vmax = fmaxf(vmax, __shfl_xor(vmax, 32));
                if (!__all(vmax - mrun <= 11.5f)) {
                    float nm = fmaxf(mrun, vmax);
                    float alpha = exp2f(mrun - nm);
                    mrun = nm;
                    lrun *= alpha;
#pragma unroll
                    for (int dt = 0; dt < 8; dt++) o[dt] *= alpha;
                }
                float rs = 0.f;
#pragma unroll
                for (int c = 0; c < 4; c++)
#pragma unroll
                    for (int r = 0; r < 4; r++) {
                        float pv = exp2f(sf[c][r] - mrun);
                        sf[c][r] = pv;
                        rs += pv;
                    }
                rs += __shfl_xor(rs, 16);
                rs += __shfl_xor(rs, 32);
                lrun += rs;
            }
#pragma unroll
            for (int c = 0; c < 4; c++) {
                ushort4 u2;
                u2.x = f2bf(sf[c][0]); u2.y = f2bf(sf[c][1]);
                u2.z = f2bf(sf[c][2]); u2.w = f2bf(sf[c][3]);
                *(ushort4*)&Pls[w][fr * 64 + ((c * 16 + g * 4) ^ ((fr & 7) << 3))] = u2;
            }
            bf16x8 pa[2];
#pragma unroll
            for (int hh = 0; hh < 2; hh++)
                pa[hh] = *(const bf16x8*)&Pls[w][fr * 64 + ((hh * 32 + g * 8) ^ ((fr & 7) << 3))];
            __builtin_amdgcn_s_setprio(1);
#pragma unroll
            for (int dt = 0; dt < 8; dt++) {
                const int vrow = dt * 16 + fr;
#pragma unroll
                for (int hh = 0; hh < 2; hh++) {
                    bf16x8 vb = *(const bf16x8*)&Vs[vrow * 64 + (((hh * 4 + g) ^ (vrow & 7)) * 8)];
                    o[dt] = __builtin_amdgcn_mfma_f32_16x16x32_bf16(vb, pa[hh], o[dt], 0, 0, 0);
                }
            }
            __builtin_amdgcn_s_setprio(0);
        }
        __syncthreads();
    }
    flush();
}

extern "C" void kernel_launch(void* const* d_in, const int* in_sizes, int n_in,
                              void* d_out, int out_size, void* d_ws, size_t ws_size,
                              hipStream_t stream) {
    const float* hs = (const float*)d_in[0];
    const float* Wq = (const float*)d_in[1];
    const float* Wk = (const float*)d_in[2];
    const float* Wv = (const float*)d_in[3];
    const float* Wo = (const float*)d_in[4];
    float* out = (float*)d_out;

    size_t off = 0;
    char* wsb = (char*)d_ws;
    auto carve = [&](size_t bytes) { void* p = wsb + off; off += bytes; return p; };

    ushort_t* Xb   = (ushort_t*)carve((size_t)M_ROWS * DMODEL * 2);
    ushort_t* Wqb  = (ushort_t*)carve((size_t)DMODEL * DMODEL * 2); // Wq|Wk|Wv|Wo contiguous
    ushort_t* Wkb  = (ushort_t*)carve((size_t)DMODEL * DMODEL * 2);
    ushort_t* Wvb  = (ushort_t*)carve((size_t)DMODEL * DMODEL * 2);
    ushort_t* Wob  = (ushort_t*)carve((size_t)DMODEL * DMODEL * 2);
    ushort_t* Qb   = (ushort_t*)carve((size_t)BATCH * NH * S_LEN * HDIM * 2);
    ushort_t* Kb   = (ushort_t*)carve((size_t)BATCH * NH * S_LEN * HDIM * 2);
    ushort_t* Vtb  = (ushort_t*)carve((size_t)BATCH * NH * S_LEN * HDIM * 2);
    ushort_t* ctxb = (ushort_t*)carve((size_t)M_ROWS * DMODEL * 2);
    float* cosT    = (float*)carve((size_t)S_LEN * 64 * 4);
    float* sinT    = (float*)carve((size_t)S_LEN * 64 * 4);

    const int nX = M_ROWS * DMODEL;   // 8388608
    const int nW = DMODEL * DMODEL;   // 4194304

    cvt_bf16<<<(nX / 4) / 256, 256, 0, stream>>>(hs, Xb, nX / 4);
    cvt4_bf16<<<dim3((nW / 4) / 256, 4), 256, 0, stream>>>(Wq, Wk, Wv, Wo, Wqb, nW / 4);
    rope_tables<<<(S_LEN * 64) / 256, 256, 0, stream>>>(cosT, sinT);

    // Fused QKV projection: A = Xb [4096][2048], B = Wqb..Wvb as [6144][2048].
    gemm128<0, 3><<<(M_ROWS / 128) * (3 * DMODEL / 192), 256, 0, stream>>>(
        Xb, Wqb, Qb, Kb, Vtb, 3 * DMODEL / 192, DMODEL);

    // Vectorized RoPE: 65536 rows x 8 threads = 2048 blocks.
    rope_inplace_v2<<<(BATCH * NH * S_LEN * 8) / 256, 256, 0, stream>>>(Qb, Kb, cosT, sinT);

    attn_fwd_v6<<<512, 256, 0, stream>>>(Qb, Kb, Vtb, ctxb);

    // Output projection: BM=128, BN=128 -> grid 32 x 16 = 512 blocks = 1 pair-round.
    gemm128<2, 2><<<(M_ROWS / 128) * (DMODEL / 128), 256, 0, stream>>>(
        ctxb, Wob, out, nullptr, nullptr, DMODEL / 128, DMODEL);
}